// Round 6
// baseline (214.519 us; speedup 1.0000x reference)
//
#include <hip/hip_runtime.h>
#include <math.h>

#define L_      73728      // t*w*h = 8*96*96
#define CTHW_   221184     // c*t*w*h
#define CH_     64         // scan chunk length
#define NCK_    1152       // chunks per batch (L_/CH_)
#define STRD_   68         // padded LDS field stride
#define LOG2E_  1.4426950408889634f

// padded conv buffers: [ch][z 0..9][y 0..97][x 0..97], interior at +1
#define PZS_    9604       // z-stride = 98*98
#define PCS_    96040      // channel stride = 10*9604
#define XPAD_N  576240     // 2*3*PCS_
#define T1P_N   3073280    // 2*16*PCS_
#define YMP_N   576240     // 2*3*PCS_
#define ZERO_N  (XPAD_N + T1P_N + YMP_N + 16)

__device__ __forceinline__ float silu_(float x) {
    return x / (1.f + __expf(-x));
}
__device__ __forceinline__ float softplus_(float x) {
    return (x > 20.f) ? x : log1pf(__expf(x));
}

// ---------------- K0a: zero the padded buffers ----------------
__global__ __launch_bounds__(256) void k0_zero(float4* __restrict__ p, int n4) {
    int i = blockIdx.x * 256 + threadIdx.x;
    if (i < n4) p[i] = make_float4(0.f, 0.f, 0.f, 0.f);
}

// ---------------- K0b: copy x -> xpad interior ----------------
__global__ __launch_bounds__(256) void k0_copy(const float* __restrict__ x,
        float* __restrict__ xpad) {
    int idx = blockIdx.x * 256 + threadIdx.x;   // 442368 total
    int xx = idx % 96, yy = (idx / 96) % 96, z = (idx / 9216) % 8, bc = idx / 73728;
    xpad[bc * PCS_ + (z + 1) * PZS_ + (yy + 1) * 98 + (xx + 1)] = x[idx];
}

// ---------------- K1: conv3d 3->16 + bias + relu (branch-free) ----------------
__global__ __launch_bounds__(256) void k1_conv(const float* __restrict__ xpad,
        const float* __restrict__ W, const float* __restrict__ b,
        float* __restrict__ t1p) {
    __shared__ float ws[81][16];
    __shared__ float bs[16];
    int tid = threadIdx.x;
    for (int i = tid; i < 1296; i += 256) ws[i % 81][i / 81] = W[i];
    if (tid < 16) bs[tid] = b[tid];
    __syncthreads();
    int idx = blockIdx.x * 256 + tid;
    int xx = idx % 96, yy = (idx / 96) % 96, tz = (idx / 9216) % 8, bb = idx / 73728;
    float acc[16];
    #pragma unroll
    for (int o = 0; o < 16; ++o) acc[o] = bs[o];
    int pbase = (tz + 1) * PZS_ + (yy + 1) * 98 + (xx + 1);
    #pragma unroll
    for (int ic = 0; ic < 3; ++ic) {
        const float* xp = xpad + (bb * 3 + ic) * PCS_ + pbase;
        float v[27];
        #pragma unroll
        for (int kz = 0; kz < 3; ++kz)
            #pragma unroll
            for (int ky = 0; ky < 3; ++ky)
                #pragma unroll
                for (int kx = 0; kx < 3; ++kx)
                    v[kz * 9 + ky * 3 + kx] = xp[(kz - 1) * PZS_ + (ky - 1) * 98 + (kx - 1)];
        #pragma unroll
        for (int k = 0; k < 27; ++k)
            #pragma unroll
            for (int o = 0; o < 16; ++o)
                acc[o] = fmaf(ws[ic * 27 + k][o], v[k], acc[o]);
    }
    float* op = t1p + bb * 16 * PCS_ + pbase;
    #pragma unroll
    for (int o = 0; o < 16; ++o) op[o * PCS_] = fmaxf(acc[o], 0.f);
}

// ---------------- K2: conv3d 16->3 + bias + residual (x4 register-blocked) ----------------
// grid: 36864 threads = 2 batch * 8 z * 96 y * 24 x-groups  -> 144 blocks
__global__ __launch_bounds__(256) void k2_conv(const float* __restrict__ t1p,
        const float* __restrict__ W, const float* __restrict__ b,
        const float* __restrict__ x, float* __restrict__ xr) {
    __shared__ float ws[432][3];
    __shared__ float bs[3];
    int tid = threadIdx.x;
    for (int i = tid; i < 1296; i += 256) ws[i % 432][i / 432] = W[i];
    if (tid < 3) bs[tid] = b[tid];
    __syncthreads();
    int idx = blockIdx.x * 256 + tid;          // 36864 total
    int xg = idx % 24, yy = (idx / 24) % 96, tz = (idx / 2304) % 8, bb = idx / 18432;
    int x0 = xg * 4;
    float acc[3][4];
    #pragma unroll
    for (int o = 0; o < 3; ++o)
        #pragma unroll
        for (int u = 0; u < 4; ++u) acc[o][u] = bs[o];
    int pbase = (tz + 1) * PZS_ + (yy + 1) * 98 + (x0 + 1);
    #pragma unroll 2
    for (int ic = 0; ic < 16; ++ic) {
        const float* xp = t1p + (bb * 16 + ic) * PCS_ + pbase;
        float v[9][6];
        #pragma unroll
        for (int kz = 0; kz < 3; ++kz)
            #pragma unroll
            for (int ky = 0; ky < 3; ++ky)
                #pragma unroll
                for (int j = 0; j < 6; ++j)
                    v[kz * 3 + ky][j] = xp[(kz - 1) * PZS_ + (ky - 1) * 98 + (j - 1)];
        #pragma unroll
        for (int kz = 0; kz < 3; ++kz)
            #pragma unroll
            for (int ky = 0; ky < 3; ++ky)
                #pragma unroll
                for (int kx = 0; kx < 3; ++kx) {
                    int k = ic * 27 + kz * 9 + ky * 3 + kx;
                    float w0 = ws[k][0], w1 = ws[k][1], w2 = ws[k][2];
                    #pragma unroll
                    for (int u = 0; u < 4; ++u) {
                        float vv = v[kz * 3 + ky][kx + u];
                        acc[0][u] = fmaf(w0, vv, acc[0][u]);
                        acc[1][u] = fmaf(w1, vv, acc[1][u]);
                        acc[2][u] = fmaf(w2, vv, acc[2][u]);
                    }
                }
    }
    int sp = tz * 9216 + yy * 96 + x0;
    #pragma unroll
    for (int o = 0; o < 3; ++o)
        #pragma unroll
        for (int u = 0; u < 4; ++u) {
            int gi = (bb * 3 + o) * 73728 + sp + u;
            xr[gi] = acc[o][u] + x[gi];
        }
}

// ---------------- K4: fused featurizer + per-chunk scan carries ----------------
// LDS fields: 0-5 xc, 6-11 dt, 12-27 B
__global__ __launch_bounds__(128) void k4_carry(const float* __restrict__ xr,
        const float* __restrict__ W_in, const float* __restrict__ W_conv,
        const float* __restrict__ b_conv, const float* __restrict__ W_xproj,
        const float* __restrict__ W_dt, const float* __restrict__ b_dt,
        const float* __restrict__ A_log, float2* __restrict__ carries) {
    __shared__ float sf[28 * STRD_];
    __shared__ float s_Win[18], s_Wc[24], s_bc[6], s_Wx[102], s_Wdt[6], s_bdt[6];
    int tid = threadIdx.x;
    if (tid < 18) s_Win[tid] = W_in[tid];
    if (tid < 24) s_Wc[tid] = W_conv[tid];
    if (tid >= 32 && tid < 38) s_bc[tid - 32] = b_conv[tid - 32];
    if (tid >= 40 && tid < 46) { s_Wdt[tid - 40] = W_dt[tid - 40]; s_bdt[tid - 40] = b_dt[tid - 40]; }
    if (tid >= 64 && tid < 128) {
        for (int i = tid - 64; i < 102; i += 64) s_Wx[i] = W_xproj[i];
    }
    __syncthreads();
    int blk = blockIdx.x, b = blk / NCK_, ck = blk % NCK_;
    if (tid < CH_) {
        int l = ck * CH_ + tid;
        const float* xb = xr + b * CTHW_;
        float xin[4][6];
        #pragma unroll
        for (int k = 0; k < 4; ++k) {
            int r = l - 3 + k;
            float a0 = 0.f, a1 = 0.f, a2v = 0.f;
            if (r >= 0) { a0 = xb[3 * r]; a1 = xb[3 * r + 1]; a2v = xb[3 * r + 2]; }
            #pragma unroll
            for (int d = 0; d < 6; ++d)
                xin[k][d] = s_Win[d * 3] * a0 + s_Win[d * 3 + 1] * a1 + s_Win[d * 3 + 2] * a2v;
        }
        float xc[6];
        #pragma unroll
        for (int d = 0; d < 6; ++d) {
            float p = s_bc[d];
            #pragma unroll
            for (int k = 0; k < 4; ++k) p = fmaf(s_Wc[d * 4 + k], xin[k][d], p);
            xc[d] = silu_(p);
        }
        float dtraw = 0.f;
        #pragma unroll
        for (int d = 0; d < 6; ++d) dtraw = fmaf(s_Wx[d], xc[d], dtraw);
        #pragma unroll
        for (int d = 0; d < 6; ++d) {
            sf[(0 + d) * STRD_ + tid] = xc[d];
            sf[(6 + d) * STRD_ + tid] = softplus_(fmaf(dtraw, s_Wdt[d], s_bdt[d]));
        }
        #pragma unroll
        for (int s = 0; s < 16; ++s) {
            float pb = 0.f;
            #pragma unroll
            for (int d = 0; d < 6; ++d) pb = fmaf(s_Wx[(1 + s) * 6 + d], xc[d], pb);
            sf[(12 + s) * STRD_ + tid] = pb;
        }
    }
    __syncthreads();
    if (tid < 96) {
        int d = tid >> 4, s = tid & 15;
        float a2 = -__expf(A_log[tid]) * LOG2E_;
        float h = 0.f, sdt = 0.f;
        #pragma unroll 8
        for (int i = 0; i < CH_; ++i) {
            float dt = sf[(6 + d) * STRD_ + i];
            float xcv = sf[d * STRD_ + i];
            float Bv = sf[(12 + s) * STRD_ + i];
            h = fmaf(exp2f(dt * a2), h, dt * xcv * Bv);
            sdt += dt;
        }
        // transposed layout for k5 float4 loads
        carries[(size_t)(b * 96 + tid) * NCK_ + ck] = make_float2(exp2f(sdt * a2), h);
    }
}

// ---------------- K5: parallel scan of carries (one block per (b,r); 2 chunks/thread) ----------------
__global__ __launch_bounds__(576) void k5_scan(const float2* __restrict__ carries,
        float* __restrict__ hpref) {
    __shared__ float2 s0[576], s1[576];
    int t = threadIdx.x;
    int blk = blockIdx.x, b = blk / 96, r = blk % 96;
    const float4* cp = (const float4*)(carries + (size_t)(b * 96 + r) * NCK_);
    float4 cc = cp[t];                          // chunks 2t (x,y) and 2t+1 (z,w)
    float2 c0 = make_float2(cc.x, cc.y);
    s0[t] = make_float2(cc.x * cc.z, cc.z * cc.y + cc.w);   // pair aggregate
    __syncthreads();
    float2* cur = s0;
    float2* nxt = s1;
    for (int off = 1; off < 576; off <<= 1) {
        float2 v = cur[t];
        if (t >= off) {
            float2 p = cur[t - off];
            v = make_float2(p.x * v.x, v.x * p.y + v.y);
        }
        nxt[t] = v;
        __syncthreads();
        float2* tmp = cur; cur = nxt; nxt = tmp;
    }
    float Ey = (t == 0) ? 0.f : cur[t - 1].y;   // state entering chunk 2t
    hpref[(size_t)(b * NCK_ + 2 * t) * 96 + r] = Ey;
    hpref[(size_t)(b * NCK_ + 2 * t + 1) * 96 + r] = fmaf(c0.x, Ey, c0.y);
}

// ---------------- K6: fused featurizer + apply scan + gate + out-proj ----------------
// LDS fields: 0-5 xc, 6-11 dt, 12-17 z, 18-33 B, 34-49 C; writes padded ymp
__global__ __launch_bounds__(128) void k6_apply(const float* __restrict__ xr,
        const float* __restrict__ W_in, const float* __restrict__ W_conv,
        const float* __restrict__ b_conv, const float* __restrict__ W_xproj,
        const float* __restrict__ W_dt, const float* __restrict__ b_dt,
        const float* __restrict__ A_log, const float* __restrict__ Dp,
        const float* __restrict__ W_out, const float* __restrict__ hpref,
        float* __restrict__ ymp) {
    __shared__ float sf[50 * STRD_];
    __shared__ float ys[CH_ * 7];
    __shared__ float s_Win[36], s_Wc[24], s_bc[6], s_Wx[198], s_Wdt[6], s_bdt[6], s_wout[18];
    int tid = threadIdx.x;
    if (tid < 36) s_Win[tid] = W_in[tid];
    if (tid < 24) s_Wc[tid] = W_conv[tid];
    if (tid >= 36 && tid < 42) s_bc[tid - 36] = b_conv[tid - 36];
    if (tid >= 42 && tid < 48) { s_Wdt[tid - 42] = W_dt[tid - 42]; s_bdt[tid - 42] = b_dt[tid - 42]; }
    if (tid >= 48 && tid < 66) s_wout[tid - 48] = W_out[tid - 48];
    if (tid >= 64 && tid < 128) {
        for (int i = tid - 64; i < 198; i += 64) s_Wx[i] = W_xproj[i];
    }
    __syncthreads();
    int blk = blockIdx.x, b = blk / NCK_, ck = blk % NCK_;
    int l = ck * CH_ + (tid & (CH_ - 1));
    if (tid < CH_) {
        const float* xb = xr + b * CTHW_;
        float xin[4][6];
        float zv[6];
        #pragma unroll
        for (int k = 0; k < 4; ++k) {
            int r = l - 3 + k;
            float a0 = 0.f, a1 = 0.f, a2v = 0.f;
            if (r >= 0) { a0 = xb[3 * r]; a1 = xb[3 * r + 1]; a2v = xb[3 * r + 2]; }
            #pragma unroll
            for (int d = 0; d < 6; ++d)
                xin[k][d] = s_Win[d * 3] * a0 + s_Win[d * 3 + 1] * a1 + s_Win[d * 3 + 2] * a2v;
            if (k == 3) {
                #pragma unroll
                for (int d = 0; d < 6; ++d)
                    zv[d] = s_Win[(6 + d) * 3] * a0 + s_Win[(6 + d) * 3 + 1] * a1 + s_Win[(6 + d) * 3 + 2] * a2v;
            }
        }
        float xc[6];
        #pragma unroll
        for (int d = 0; d < 6; ++d) {
            float p = s_bc[d];
            #pragma unroll
            for (int k = 0; k < 4; ++k) p = fmaf(s_Wc[d * 4 + k], xin[k][d], p);
            xc[d] = silu_(p);
        }
        float dtraw = 0.f;
        #pragma unroll
        for (int d = 0; d < 6; ++d) dtraw = fmaf(s_Wx[d], xc[d], dtraw);
        #pragma unroll
        for (int d = 0; d < 6; ++d) {
            sf[(0 + d) * STRD_ + tid] = xc[d];
            sf[(6 + d) * STRD_ + tid] = softplus_(fmaf(dtraw, s_Wdt[d], s_bdt[d]));
            sf[(12 + d) * STRD_ + tid] = zv[d];
        }
        #pragma unroll
        for (int s = 0; s < 16; ++s) {
            float pb = 0.f, pc = 0.f;
            #pragma unroll
            for (int d = 0; d < 6; ++d) {
                pb = fmaf(s_Wx[(1 + s) * 6 + d], xc[d], pb);
                pc = fmaf(s_Wx[(17 + s) * 6 + d], xc[d], pc);
            }
            sf[(18 + s) * STRD_ + tid] = pb;
            sf[(34 + s) * STRD_ + tid] = pc;
        }
    }
    __syncthreads();
    // --- scan + y, deferred shfl reduction (8-wide batches) ---
    if (tid < 96) {
        int d = tid >> 4, s = tid & 15;
        float a2 = -__expf(A_log[tid]) * LOG2E_;
        float Dd = Dp[d];
        float h = hpref[(size_t)(b * NCK_ + ck) * 96 + tid];
        #pragma unroll 2
        for (int i0 = 0; i0 < CH_; i0 += 8) {
            float pb[8], xv[8];
            #pragma unroll
            for (int j = 0; j < 8; ++j) {
                int i = i0 + j;
                float dt = sf[(6 + d) * STRD_ + i];
                float xcv = sf[d * STRD_ + i];
                float Bv = sf[(18 + s) * STRD_ + i];
                float Cv = sf[(34 + s) * STRD_ + i];
                h = fmaf(exp2f(dt * a2), h, dt * xcv * Bv);
                pb[j] = h * Cv;
                xv[j] = xcv;
            }
            #pragma unroll
            for (int j = 0; j < 8; ++j) pb[j] += __shfl_xor(pb[j], 1, 16);
            #pragma unroll
            for (int j = 0; j < 8; ++j) pb[j] += __shfl_xor(pb[j], 2, 16);
            #pragma unroll
            for (int j = 0; j < 8; ++j) pb[j] += __shfl_xor(pb[j], 4, 16);
            #pragma unroll
            for (int j = 0; j < 8; ++j) pb[j] += __shfl_xor(pb[j], 8, 16);
            if (s == 0) {
                #pragma unroll
                for (int j = 0; j < 8; ++j) {
                    float zz = sf[(12 + d) * STRD_ + i0 + j];
                    ys[(i0 + j) * 7 + d] = fmaf(xv[j], Dd, pb[j]) * silu_(zz);
                }
            }
        }
    }
    __syncthreads();
    // --- out-proj: thread tid (<CH_) handles token l; write padded ymp interior ---
    if (tid < CH_) {
        float y0 = ys[tid * 7 + 0], y1 = ys[tid * 7 + 1], y2 = ys[tid * 7 + 2];
        float y3 = ys[tid * 7 + 3], y4 = ys[tid * 7 + 4], y5 = ys[tid * 7 + 5];
        int xx = l % 96, yy = (l / 96) % 96, tz = l / 9216;
        int pdst = (tz + 1) * PZS_ + (yy + 1) * 98 + (xx + 1);
        #pragma unroll
        for (int i = 0; i < 3; ++i) {
            float o = s_wout[i * 6 + 0] * y0 + s_wout[i * 6 + 1] * y1
                    + s_wout[i * 6 + 2] * y2 + s_wout[i * 6 + 3] * y3
                    + s_wout[i * 6 + 4] * y4 + s_wout[i * 6 + 5] * y5;
            ymp[(b * 3 + i) * PCS_ + pdst] = o;
        }
    }
}

// ---------------- K7: final conv3d 3->3 + bias (x4 register-blocked) ----------------
// grid: 36864 threads -> 144 blocks
__global__ __launch_bounds__(256) void k7_conv(const float* __restrict__ ymp,
        const float* __restrict__ W, const float* __restrict__ b,
        float* __restrict__ out) {
    __shared__ float ws[81][3];
    __shared__ float bs[3];
    int tid = threadIdx.x;
    for (int i = tid; i < 243; i += 256) ws[i % 81][i / 81] = W[i];
    if (tid < 3) bs[tid] = b[tid];
    __syncthreads();
    int idx = blockIdx.x * 256 + tid;          // 36864 total
    int xg = idx % 24, yy = (idx / 24) % 96, tz = (idx / 2304) % 8, bb = idx / 18432;
    int x0 = xg * 4;
    float acc[3][4];
    #pragma unroll
    for (int o = 0; o < 3; ++o)
        #pragma unroll
        for (int u = 0; u < 4; ++u) acc[o][u] = bs[o];
    int pbase = (tz + 1) * PZS_ + (yy + 1) * 98 + (x0 + 1);
    #pragma unroll
    for (int ic = 0; ic < 3; ++ic) {
        const float* xp = ymp + (bb * 3 + ic) * PCS_ + pbase;
        float v[9][6];
        #pragma unroll
        for (int kz = 0; kz < 3; ++kz)
            #pragma unroll
            for (int ky = 0; ky < 3; ++ky)
                #pragma unroll
                for (int j = 0; j < 6; ++j)
                    v[kz * 3 + ky][j] = xp[(kz - 1) * PZS_ + (ky - 1) * 98 + (j - 1)];
        #pragma unroll
        for (int kz = 0; kz < 3; ++kz)
            #pragma unroll
            for (int ky = 0; ky < 3; ++ky)
                #pragma unroll
                for (int kx = 0; kx < 3; ++kx) {
                    int k = ic * 27 + kz * 9 + ky * 3 + kx;
                    float w0 = ws[k][0], w1 = ws[k][1], w2 = ws[k][2];
                    #pragma unroll
                    for (int u = 0; u < 4; ++u) {
                        float vv = v[kz * 3 + ky][kx + u];
                        acc[0][u] = fmaf(w0, vv, acc[0][u]);
                        acc[1][u] = fmaf(w1, vv, acc[1][u]);
                        acc[2][u] = fmaf(w2, vv, acc[2][u]);
                    }
                }
    }
    int sp = tz * 9216 + yy * 96 + x0;
    #pragma unroll
    for (int o = 0; o < 3; ++o)
        #pragma unroll
        for (int u = 0; u < 4; ++u)
            out[(bb * 3 + o) * 73728 + sp + u] = acc[o][u];
}

extern "C" void kernel_launch(void* const* d_in, const int* in_sizes, int n_in,
                              void* d_out, int out_size, void* d_ws, size_t ws_size,
                              hipStream_t stream) {
    const float* x      = (const float*)d_in[0];
    const float* W_cb1  = (const float*)d_in[1];
    const float* b_cb1  = (const float*)d_in[2];
    const float* W_cb2  = (const float*)d_in[3];
    const float* b_cb2  = (const float*)d_in[4];
    const float* W_in   = (const float*)d_in[5];
    const float* W_conv = (const float*)d_in[6];
    const float* b_conv = (const float*)d_in[7];
    const float* W_xpr  = (const float*)d_in[8];
    const float* W_dt   = (const float*)d_in[9];
    const float* b_dt   = (const float*)d_in[10];
    const float* A_log  = (const float*)d_in[11];
    const float* Dp     = (const float*)d_in[12];
    const float* W_out  = (const float*)d_in[13];
    const float* W_sm   = (const float*)d_in[14];
    const float* b_sm   = (const float*)d_in[15];

    float* ws    = (float*)d_ws;
    float* xpad  = ws;                        // XPAD_N
    float* t1p   = xpad + XPAD_N;             // T1P_N
    float* ymp   = t1p + T1P_N;               // YMP_N
    float* xr    = ws + ZERO_N;               // 442368
    float2* carr = (float2*)(xr + 442368);    // 2*96*1152 float2 = 442368 floats
    float* hpref = xr + 442368 + 442368;      // 2*1152*96 = 221184
    float* out   = (float*)d_out;

    int n4 = ZERO_N / 4;
    k0_zero<<<(n4 + 255) / 256, 256, 0, stream>>>((float4*)ws, n4);
    k0_copy<<<1728, 256, 0, stream>>>(x, xpad);
    k1_conv<<<576, 256, 0, stream>>>(xpad, W_cb1, b_cb1, t1p);
    k2_conv<<<144, 256, 0, stream>>>(t1p, W_cb2, b_cb2, x, xr);
    k4_carry<<<2304, 128, 0, stream>>>(xr, W_in, W_conv, b_conv, W_xpr, W_dt, b_dt, A_log, carr);
    k5_scan<<<192, 576, 0, stream>>>(carr, hpref);
    k6_apply<<<2304, 128, 0, stream>>>(xr, W_in, W_conv, b_conv, W_xpr, W_dt, b_dt,
                                       A_log, Dp, W_out, hpref, ymp);
    k7_conv<<<144, 256, 0, stream>>>(ymp, W_sm, b_sm, out);
}

// Round 13
// 191.271 us; speedup vs baseline: 1.1215x; 1.1215x over previous
//
#include <hip/hip_runtime.h>
#include <math.h>

#define L_      73728      // t*w*h = 8*96*96
#define CTHW_   221184     // c*t*w*h
#define CH_     64         // scan chunk length
#define NCK_    1152       // chunks per batch (L_/CH_)
#define STRD_   68         // padded LDS field stride
#define LOG2E_  1.4426950408889634f

// padded conv buffers: [ch][z 0..9][y 0..97][x 0..97], interior at +1
#define PZS_    9604       // z-stride = 98*98
#define PCS_    96040      // channel stride = 10*9604
#define XPAD_N  576240     // 2*3*PCS_
#define T1P_N   3073280    // 2*16*PCS_
#define YMP_N   576240     // 2*3*PCS_
#define ZERO_N  (XPAD_N + T1P_N + YMP_N + 16)

__device__ __forceinline__ float silu_(float x) {
    return x / (1.f + __expf(-x));
}
__device__ __forceinline__ float softplus_(float x) {
    return (x > 20.f) ? x : log1pf(__expf(x));
}

// ---------------- K0a: zero the padded buffers ----------------
__global__ __launch_bounds__(256) void k0_zero(float4* __restrict__ p, int n4) {
    int i = blockIdx.x * 256 + threadIdx.x;
    if (i < n4) p[i] = make_float4(0.f, 0.f, 0.f, 0.f);
}

// ---------------- K0b: copy x -> xpad interior ----------------
__global__ __launch_bounds__(256) void k0_copy(const float* __restrict__ x,
        float* __restrict__ xpad) {
    int idx = blockIdx.x * 256 + threadIdx.x;   // 442368 total
    int xx = idx % 96, yy = (idx / 96) % 96, z = (idx / 9216) % 8, bc = idx / 73728;
    xpad[bc * PCS_ + (z + 1) * PZS_ + (yy + 1) * 98 + (xx + 1)] = x[idx];
}

// ---------------- K1: conv3d 3->16 + bias + relu (branch-free, XCD-swizzled) ----------------
// grid 576 = 8 XCD * 72
__global__ __launch_bounds__(256, 4) void k1_conv(const float* __restrict__ xpad,
        const float* __restrict__ W, const float* __restrict__ b,
        float* __restrict__ t1p) {
    __shared__ float ws[81][16];
    __shared__ float bs[16];
    int tid = threadIdx.x;
    for (int i = tid; i < 1296; i += 256) ws[i % 81][i / 81] = W[i];
    if (tid < 16) bs[tid] = b[tid];
    __syncthreads();
    int bid = blockIdx.x;
    int swz = (bid & 7) * 72 + (bid >> 3);
    int idx = swz * 256 + tid;
    int xx = idx % 96, yy = (idx / 96) % 96, tz = (idx / 9216) % 8, bb = idx / 73728;
    float acc[16];
    #pragma unroll
    for (int o = 0; o < 16; ++o) acc[o] = bs[o];
    int pbase = (tz + 1) * PZS_ + (yy + 1) * 98 + (xx + 1);
    #pragma unroll
    for (int ic = 0; ic < 3; ++ic) {
        const float* xp = xpad + (bb * 3 + ic) * PCS_ + pbase;
        float v[27];
        #pragma unroll
        for (int kz = 0; kz < 3; ++kz)
            #pragma unroll
            for (int ky = 0; ky < 3; ++ky)
                #pragma unroll
                for (int kx = 0; kx < 3; ++kx)
                    v[kz * 9 + ky * 3 + kx] = xp[(kz - 1) * PZS_ + (ky - 1) * 98 + (kx - 1)];
        #pragma unroll
        for (int k = 0; k < 27; ++k)
            #pragma unroll
            for (int o = 0; o < 16; ++o)
                acc[o] = fmaf(ws[ic * 27 + k][o], v[k], acc[o]);
    }
    float* op = t1p + bb * 16 * PCS_ + pbase;
    #pragma unroll
    for (int o = 0; o < 16; ++o) op[o * PCS_] = fmaxf(acc[o], 0.f);
}

// ---------------- K2: conv3d 16->3 + bias + residual (x1, VGPR headroom, swizzled) ----------------
// grid 576 = 8 XCD * 72
__global__ __launch_bounds__(256, 4) void k2_conv(const float* __restrict__ t1p,
        const float* __restrict__ W, const float* __restrict__ b,
        const float* __restrict__ x, float* __restrict__ xr) {
    __shared__ float ws[432][3];
    __shared__ float bs[3];
    int tid = threadIdx.x;
    for (int i = tid; i < 1296; i += 256) ws[i % 432][i / 432] = W[i];
    if (tid < 3) bs[tid] = b[tid];
    __syncthreads();
    int bid = blockIdx.x;
    int swz = (bid & 7) * 72 + (bid >> 3);
    int idx = swz * 256 + tid;
    int xx = idx % 96, yy = (idx / 96) % 96, tz = (idx / 9216) % 8, bb = idx / 73728;
    float acc[3];
    #pragma unroll
    for (int o = 0; o < 3; ++o) acc[o] = bs[o];
    int pbase = (tz + 1) * PZS_ + (yy + 1) * 98 + (xx + 1);
    #pragma unroll 2
    for (int ic = 0; ic < 16; ++ic) {
        const float* xp = t1p + (bb * 16 + ic) * PCS_ + pbase;
        float v[27];
        #pragma unroll
        for (int kz = 0; kz < 3; ++kz)
            #pragma unroll
            for (int ky = 0; ky < 3; ++ky)
                #pragma unroll
                for (int kx = 0; kx < 3; ++kx)
                    v[kz * 9 + ky * 3 + kx] = xp[(kz - 1) * PZS_ + (ky - 1) * 98 + (kx - 1)];
        #pragma unroll
        for (int k = 0; k < 27; ++k)
            #pragma unroll
            for (int o = 0; o < 3; ++o)
                acc[o] = fmaf(ws[ic * 27 + k][o], v[k], acc[o]);
    }
    int sp = tz * 9216 + yy * 96 + xx;
    #pragma unroll
    for (int o = 0; o < 3; ++o) {
        int gi = (bb * 3 + o) * 73728 + sp;
        xr[gi] = acc[o] + x[gi];
    }
}

// ---------------- K4: fused featurizer + per-chunk scan carries (swizzled) ----------------
// grid 2304 = 8 XCD * 288; LDS fields: 0-5 xc, 6-11 dt, 12-27 B
__global__ __launch_bounds__(128) void k4_carry(const float* __restrict__ xr,
        const float* __restrict__ W_in, const float* __restrict__ W_conv,
        const float* __restrict__ b_conv, const float* __restrict__ W_xproj,
        const float* __restrict__ W_dt, const float* __restrict__ b_dt,
        const float* __restrict__ A_log, float2* __restrict__ carries) {
    __shared__ float sf[28 * STRD_];
    __shared__ float s_Win[18], s_Wc[24], s_bc[6], s_Wx[102], s_Wdt[6], s_bdt[6];
    int tid = threadIdx.x;
    if (tid < 18) s_Win[tid] = W_in[tid];
    if (tid < 24) s_Wc[tid] = W_conv[tid];
    if (tid >= 32 && tid < 38) s_bc[tid - 32] = b_conv[tid - 32];
    if (tid >= 40 && tid < 46) { s_Wdt[tid - 40] = W_dt[tid - 40]; s_bdt[tid - 40] = b_dt[tid - 40]; }
    if (tid >= 64 && tid < 128) {
        for (int i = tid - 64; i < 102; i += 64) s_Wx[i] = W_xproj[i];
    }
    __syncthreads();
    int bid = blockIdx.x;
    int blk = (bid & 7) * 288 + (bid >> 3);
    int b = blk / NCK_, ck = blk % NCK_;
    if (tid < CH_) {
        int l = ck * CH_ + tid;
        const float* xb = xr + b * CTHW_;
        float xin[4][6];
        #pragma unroll
        for (int k = 0; k < 4; ++k) {
            int r = l - 3 + k;
            float a0 = 0.f, a1 = 0.f, a2v = 0.f;
            if (r >= 0) { a0 = xb[3 * r]; a1 = xb[3 * r + 1]; a2v = xb[3 * r + 2]; }
            #pragma unroll
            for (int d = 0; d < 6; ++d)
                xin[k][d] = s_Win[d * 3] * a0 + s_Win[d * 3 + 1] * a1 + s_Win[d * 3 + 2] * a2v;
        }
        float xc[6];
        #pragma unroll
        for (int d = 0; d < 6; ++d) {
            float p = s_bc[d];
            #pragma unroll
            for (int k = 0; k < 4; ++k) p = fmaf(s_Wc[d * 4 + k], xin[k][d], p);
            xc[d] = silu_(p);
        }
        float dtraw = 0.f;
        #pragma unroll
        for (int d = 0; d < 6; ++d) dtraw = fmaf(s_Wx[d], xc[d], dtraw);
        #pragma unroll
        for (int d = 0; d < 6; ++d) {
            sf[(0 + d) * STRD_ + tid] = xc[d];
            sf[(6 + d) * STRD_ + tid] = softplus_(fmaf(dtraw, s_Wdt[d], s_bdt[d]));
        }
        #pragma unroll
        for (int s = 0; s < 16; ++s) {
            float pb = 0.f;
            #pragma unroll
            for (int d = 0; d < 6; ++d) pb = fmaf(s_Wx[(1 + s) * 6 + d], xc[d], pb);
            sf[(12 + s) * STRD_ + tid] = pb;
        }
    }
    __syncthreads();
    if (tid < 96) {
        int d = tid >> 4, s = tid & 15;
        float a2 = -__expf(A_log[tid]) * LOG2E_;
        float h = 0.f, sdt = 0.f;
        #pragma unroll 8
        for (int i = 0; i < CH_; ++i) {
            float dt = sf[(6 + d) * STRD_ + i];
            float xcv = sf[d * STRD_ + i];
            float Bv = sf[(12 + s) * STRD_ + i];
            h = fmaf(exp2f(dt * a2), h, dt * xcv * Bv);
            sdt += dt;
        }
        carries[(size_t)(b * 96 + tid) * NCK_ + ck] = make_float2(exp2f(sdt * a2), h);
    }
}

// ---------------- K5: parallel scan of carries (one block per (b,r); 2 chunks/thread) ----------------
__global__ __launch_bounds__(576) void k5_scan(const float2* __restrict__ carries,
        float* __restrict__ hpref) {
    __shared__ float2 s0[576], s1[576];
    int t = threadIdx.x;
    int blk = blockIdx.x, b = blk / 96, r = blk % 96;
    const float4* cp = (const float4*)(carries + (size_t)(b * 96 + r) * NCK_);
    float4 cc = cp[t];                          // chunks 2t (x,y) and 2t+1 (z,w)
    float2 c0 = make_float2(cc.x, cc.y);
    s0[t] = make_float2(cc.x * cc.z, cc.z * cc.y + cc.w);   // pair aggregate
    __syncthreads();
    float2* cur = s0;
    float2* nxt = s1;
    for (int off = 1; off < 576; off <<= 1) {
        float2 v = cur[t];
        if (t >= off) {
            float2 p = cur[t - off];
            v = make_float2(p.x * v.x, v.x * p.y + v.y);
        }
        nxt[t] = v;
        __syncthreads();
        float2* tmp = cur; cur = nxt; nxt = tmp;
    }
    float Ey = (t == 0) ? 0.f : cur[t - 1].y;   // state entering chunk 2t
    hpref[(size_t)(b * NCK_ + 2 * t) * 96 + r] = Ey;
    hpref[(size_t)(b * NCK_ + 2 * t + 1) * 96 + r] = fmaf(c0.x, Ey, c0.y);
}

// ---------------- K6: fused featurizer + apply scan + gate + out-proj (swizzled) ----------------
// grid 2304 = 8 XCD * 288; LDS fields: 0-5 xc, 6-11 dt, 12-17 z, 18-33 B, 34-49 C
__global__ __launch_bounds__(128) void k6_apply(const float* __restrict__ xr,
        const float* __restrict__ W_in, const float* __restrict__ W_conv,
        const float* __restrict__ b_conv, const float* __restrict__ W_xproj,
        const float* __restrict__ W_dt, const float* __restrict__ b_dt,
        const float* __restrict__ A_log, const float* __restrict__ Dp,
        const float* __restrict__ W_out, const float* __restrict__ hpref,
        float* __restrict__ ymp) {
    __shared__ float sf[50 * STRD_];
    __shared__ float ys[CH_ * 7];
    __shared__ float s_Win[36], s_Wc[24], s_bc[6], s_Wx[198], s_Wdt[6], s_bdt[6], s_wout[18];
    int tid = threadIdx.x;
    if (tid < 36) s_Win[tid] = W_in[tid];
    if (tid < 24) s_Wc[tid] = W_conv[tid];
    if (tid >= 36 && tid < 42) s_bc[tid - 36] = b_conv[tid - 36];
    if (tid >= 42 && tid < 48) { s_Wdt[tid - 42] = W_dt[tid - 42]; s_bdt[tid - 42] = b_dt[tid - 42]; }
    if (tid >= 48 && tid < 66) s_wout[tid - 48] = W_out[tid - 48];
    if (tid >= 64 && tid < 128) {
        for (int i = tid - 64; i < 198; i += 64) s_Wx[i] = W_xproj[i];
    }
    __syncthreads();
    int bid = blockIdx.x;
    int blk = (bid & 7) * 288 + (bid >> 3);
    int b = blk / NCK_, ck = blk % NCK_;
    int l = ck * CH_ + (tid & (CH_ - 1));
    if (tid < CH_) {
        const float* xb = xr + b * CTHW_;
        float xin[4][6];
        float zv[6];
        #pragma unroll
        for (int k = 0; k < 4; ++k) {
            int r = l - 3 + k;
            float a0 = 0.f, a1 = 0.f, a2v = 0.f;
            if (r >= 0) { a0 = xb[3 * r]; a1 = xb[3 * r + 1]; a2v = xb[3 * r + 2]; }
            #pragma unroll
            for (int d = 0; d < 6; ++d)
                xin[k][d] = s_Win[d * 3] * a0 + s_Win[d * 3 + 1] * a1 + s_Win[d * 3 + 2] * a2v;
            if (k == 3) {
                #pragma unroll
                for (int d = 0; d < 6; ++d)
                    zv[d] = s_Win[(6 + d) * 3] * a0 + s_Win[(6 + d) * 3 + 1] * a1 + s_Win[(6 + d) * 3 + 2] * a2v;
            }
        }
        float xc[6];
        #pragma unroll
        for (int d = 0; d < 6; ++d) {
            float p = s_bc[d];
            #pragma unroll
            for (int k = 0; k < 4; ++k) p = fmaf(s_Wc[d * 4 + k], xin[k][d], p);
            xc[d] = silu_(p);
        }
        float dtraw = 0.f;
        #pragma unroll
        for (int d = 0; d < 6; ++d) dtraw = fmaf(s_Wx[d], xc[d], dtraw);
        #pragma unroll
        for (int d = 0; d < 6; ++d) {
            sf[(0 + d) * STRD_ + tid] = xc[d];
            sf[(6 + d) * STRD_ + tid] = softplus_(fmaf(dtraw, s_Wdt[d], s_bdt[d]));
            sf[(12 + d) * STRD_ + tid] = zv[d];
        }
        #pragma unroll
        for (int s = 0; s < 16; ++s) {
            float pb = 0.f, pc = 0.f;
            #pragma unroll
            for (int d = 0; d < 6; ++d) {
                pb = fmaf(s_Wx[(1 + s) * 6 + d], xc[d], pb);
                pc = fmaf(s_Wx[(17 + s) * 6 + d], xc[d], pc);
            }
            sf[(18 + s) * STRD_ + tid] = pb;
            sf[(34 + s) * STRD_ + tid] = pc;
        }
    }
    __syncthreads();
    // --- scan + y, deferred shfl reduction (8-wide batches) ---
    if (tid < 96) {
        int d = tid >> 4, s = tid & 15;
        float a2 = -__expf(A_log[tid]) * LOG2E_;
        float Dd = Dp[d];
        float h = hpref[(size_t)(b * NCK_ + ck) * 96 + tid];
        #pragma unroll 2
        for (int i0 = 0; i0 < CH_; i0 += 8) {
            float pb[8], xv[8];
            #pragma unroll
            for (int j = 0; j < 8; ++j) {
                int i = i0 + j;
                float dt = sf[(6 + d) * STRD_ + i];
                float xcv = sf[d * STRD_ + i];
                float Bv = sf[(18 + s) * STRD_ + i];
                float Cv = sf[(34 + s) * STRD_ + i];
                h = fmaf(exp2f(dt * a2), h, dt * xcv * Bv);
                pb[j] = h * Cv;
                xv[j] = xcv;
            }
            #pragma unroll
            for (int j = 0; j < 8; ++j) pb[j] += __shfl_xor(pb[j], 1, 16);
            #pragma unroll
            for (int j = 0; j < 8; ++j) pb[j] += __shfl_xor(pb[j], 2, 16);
            #pragma unroll
            for (int j = 0; j < 8; ++j) pb[j] += __shfl_xor(pb[j], 4, 16);
            #pragma unroll
            for (int j = 0; j < 8; ++j) pb[j] += __shfl_xor(pb[j], 8, 16);
            if (s == 0) {
                #pragma unroll
                for (int j = 0; j < 8; ++j) {
                    float zz = sf[(12 + d) * STRD_ + i0 + j];
                    ys[(i0 + j) * 7 + d] = fmaf(xv[j], Dd, pb[j]) * silu_(zz);
                }
            }
        }
    }
    __syncthreads();
    // --- out-proj: thread tid (<CH_) handles token l; write padded ymp interior ---
    if (tid < CH_) {
        float y0 = ys[tid * 7 + 0], y1 = ys[tid * 7 + 1], y2 = ys[tid * 7 + 2];
        float y3 = ys[tid * 7 + 3], y4 = ys[tid * 7 + 4], y5 = ys[tid * 7 + 5];
        int xx = l % 96, yy = (l / 96) % 96, tz = l / 9216;
        int pdst = (tz + 1) * PZS_ + (yy + 1) * 98 + (xx + 1);
        #pragma unroll
        for (int i = 0; i < 3; ++i) {
            float o = s_wout[i * 6 + 0] * y0 + s_wout[i * 6 + 1] * y1
                    + s_wout[i * 6 + 2] * y2 + s_wout[i * 6 + 3] * y3
                    + s_wout[i * 6 + 4] * y4 + s_wout[i * 6 + 5] * y5;
            ymp[(b * 3 + i) * PCS_ + pdst] = o;
        }
    }
}

// ---------------- K7: final conv3d 3->3 + bias (x1, swizzled) ----------------
// grid 576 = 8 XCD * 72
__global__ __launch_bounds__(256, 4) void k7_conv(const float* __restrict__ ymp,
        const float* __restrict__ W, const float* __restrict__ b,
        float* __restrict__ out) {
    __shared__ float ws[81][3];
    __shared__ float bs[3];
    int tid = threadIdx.x;
    for (int i = tid; i < 243; i += 256) ws[i % 81][i / 81] = W[i];
    if (tid < 3) bs[tid] = b[tid];
    __syncthreads();
    int bid = blockIdx.x;
    int swz = (bid & 7) * 72 + (bid >> 3);
    int idx = swz * 256 + tid;
    int xx = idx % 96, yy = (idx / 96) % 96, tz = (idx / 9216) % 8, bb = idx / 73728;
    float acc[3];
    #pragma unroll
    for (int o = 0; o < 3; ++o) acc[o] = bs[o];
    int pbase = (tz + 1) * PZS_ + (yy + 1) * 98 + (xx + 1);
    #pragma unroll
    for (int ic = 0; ic < 3; ++ic) {
        const float* xp = ymp + (bb * 3 + ic) * PCS_ + pbase;
        float v[27];
        #pragma unroll
        for (int kz = 0; kz < 3; ++kz)
            #pragma unroll
            for (int ky = 0; ky < 3; ++ky)
                #pragma unroll
                for (int kx = 0; kx < 3; ++kx)
                    v[kz * 9 + ky * 3 + kx] = xp[(kz - 1) * PZS_ + (ky - 1) * 98 + (kx - 1)];
        #pragma unroll
        for (int k = 0; k < 27; ++k)
            #pragma unroll
            for (int o = 0; o < 3; ++o)
                acc[o] = fmaf(ws[ic * 27 + k][o], v[k], acc[o]);
    }
    int sp = tz * 9216 + yy * 96 + xx;
    #pragma unroll
    for (int o = 0; o < 3; ++o) out[(bb * 3 + o) * 73728 + sp] = acc[o];
}

extern "C" void kernel_launch(void* const* d_in, const int* in_sizes, int n_in,
                              void* d_out, int out_size, void* d_ws, size_t ws_size,
                              hipStream_t stream) {
    const float* x      = (const float*)d_in[0];
    const float* W_cb1  = (const float*)d_in[1];
    const float* b_cb1  = (const float*)d_in[2];
    const float* W_cb2  = (const float*)d_in[3];
    const float* b_cb2  = (const float*)d_in[4];
    const float* W_in   = (const float*)d_in[5];
    const float* W_conv = (const float*)d_in[6];
    const float* b_conv = (const float*)d_in[7];
    const float* W_xpr  = (const float*)d_in[8];
    const float* W_dt   = (const float*)d_in[9];
    const float* b_dt   = (const float*)d_in[10];
    const float* A_log  = (const float*)d_in[11];
    const float* Dp     = (const float*)d_in[12];
    const float* W_out  = (const float*)d_in[13];
    const float* W_sm   = (const float*)d_in[14];
    const float* b_sm   = (const float*)d_in[15];

    float* ws    = (float*)d_ws;
    float* xpad  = ws;                        // XPAD_N
    float* t1p   = xpad + XPAD_N;             // T1P_N
    float* ymp   = t1p + T1P_N;               // YMP_N
    float* xr    = ws + ZERO_N;               // 442368
    float2* carr = (float2*)(xr + 442368);    // 2*96*1152 float2 = 442368 floats
    float* hpref = xr + 442368 + 442368;      // 2*1152*96 = 221184
    float* out   = (float*)d_out;

    int n4 = ZERO_N / 4;
    k0_zero<<<(n4 + 255) / 256, 256, 0, stream>>>((float4*)ws, n4);
    k0_copy<<<1728, 256, 0, stream>>>(x, xpad);
    k1_conv<<<576, 256, 0, stream>>>(xpad, W_cb1, b_cb1, t1p);
    k2_conv<<<576, 256, 0, stream>>>(t1p, W_cb2, b_cb2, x, xr);
    k4_carry<<<2304, 128, 0, stream>>>(xr, W_in, W_conv, b_conv, W_xpr, W_dt, b_dt, A_log, carr);
    k5_scan<<<192, 576, 0, stream>>>(carr, hpref);
    k6_apply<<<2304, 128, 0, stream>>>(xr, W_in, W_conv, b_conv, W_xpr, W_dt, b_dt,
                                       A_log, Dp, W_out, hpref, ymp);
    k7_conv<<<576, 256, 0, stream>>>(ymp, W_sm, b_sm, out);
}

// Round 14
// 188.974 us; speedup vs baseline: 1.1352x; 1.0122x over previous
//
#include <hip/hip_runtime.h>
#include <math.h>

#define L_      73728      // t*w*h = 8*96*96
#define CTHW_   221184     // c*t*w*h
#define CH_     64         // scan chunk length
#define NCK_    1152       // chunks per batch (L_/CH_)
#define STRD_   68         // padded LDS field stride
#define LOG2E_  1.4426950408889634f

// padded conv buffers: [ch][z 0..9][y 0..97][x 0..97], interior at +1
#define PZS_    9604       // z-stride = 98*98
#define PCS_    96040      // channel stride = 10*9604
#define XPAD_N  576240     // 2*3*PCS_
#define T1P_N   3073280    // 2*16*PCS_
#define YMP_N   576240     // 2*3*PCS_
#define ZERO_N  (XPAD_N + T1P_N + YMP_N + 16)

__device__ __forceinline__ float silu_(float x) {
    return x / (1.f + __expf(-x));
}
__device__ __forceinline__ float softplus_(float x) {
    return (x > 20.f) ? x : log1pf(__expf(x));
}

// ---------------- K0a: zero the padded buffers ----------------
__global__ __launch_bounds__(256) void k0_zero(float4* __restrict__ p, int n4) {
    int i = blockIdx.x * 256 + threadIdx.x;
    if (i < n4) p[i] = make_float4(0.f, 0.f, 0.f, 0.f);
}

// ---------------- K0b: copy x -> xpad interior ----------------
__global__ __launch_bounds__(256) void k0_copy(const float* __restrict__ x,
        float* __restrict__ xpad) {
    int idx = blockIdx.x * 256 + threadIdx.x;   // 442368 total
    int xx = idx % 96, yy = (idx / 96) % 96, z = (idx / 9216) % 8, bc = idx / 73728;
    xpad[bc * PCS_ + (z + 1) * PZS_ + (yy + 1) * 98 + (xx + 1)] = x[idx];
}

// ---------------- K1: conv3d 3->16 + bias + relu (branch-free, XCD-swizzled) ----------------
// grid 576 = 8 XCD * 72
__global__ __launch_bounds__(256, 4) void k1_conv(const float* __restrict__ xpad,
        const float* __restrict__ W, const float* __restrict__ b,
        float* __restrict__ t1p) {
    __shared__ float ws[81][16];
    __shared__ float bs[16];
    int tid = threadIdx.x;
    for (int i = tid; i < 1296; i += 256) ws[i % 81][i / 81] = W[i];
    if (tid < 16) bs[tid] = b[tid];
    __syncthreads();
    int bid = blockIdx.x;
    int swz = (bid & 7) * 72 + (bid >> 3);
    int idx = swz * 256 + tid;
    int xx = idx % 96, yy = (idx / 96) % 96, tz = (idx / 9216) % 8, bb = idx / 73728;
    float acc[16];
    #pragma unroll
    for (int o = 0; o < 16; ++o) acc[o] = bs[o];
    int pbase = (tz + 1) * PZS_ + (yy + 1) * 98 + (xx + 1);
    #pragma unroll
    for (int ic = 0; ic < 3; ++ic) {
        const float* xp = xpad + (bb * 3 + ic) * PCS_ + pbase;
        float v[27];
        #pragma unroll
        for (int kz = 0; kz < 3; ++kz)
            #pragma unroll
            for (int ky = 0; ky < 3; ++ky)
                #pragma unroll
                for (int kx = 0; kx < 3; ++kx)
                    v[kz * 9 + ky * 3 + kx] = xp[(kz - 1) * PZS_ + (ky - 1) * 98 + (kx - 1)];
        #pragma unroll
        for (int k = 0; k < 27; ++k)
            #pragma unroll
            for (int o = 0; o < 16; ++o)
                acc[o] = fmaf(ws[ic * 27 + k][o], v[k], acc[o]);
    }
    float* op = t1p + bb * 16 * PCS_ + pbase;
    #pragma unroll
    for (int o = 0; o < 16; ++o) op[o * PCS_] = fmaxf(acc[o], 0.f);
}

// ---------------- K2: conv3d 16->3 + bias + residual (x1, swizzled) ----------------
// grid 576 = 8 XCD * 72
__global__ __launch_bounds__(256, 4) void k2_conv(const float* __restrict__ t1p,
        const float* __restrict__ W, const float* __restrict__ b,
        const float* __restrict__ x, float* __restrict__ xr) {
    __shared__ float ws[432][3];
    __shared__ float bs[3];
    int tid = threadIdx.x;
    for (int i = tid; i < 1296; i += 256) ws[i % 432][i / 432] = W[i];
    if (tid < 3) bs[tid] = b[tid];
    __syncthreads();
    int bid = blockIdx.x;
    int swz = (bid & 7) * 72 + (bid >> 3);
    int idx = swz * 256 + tid;
    int xx = idx % 96, yy = (idx / 96) % 96, tz = (idx / 9216) % 8, bb = idx / 73728;
    float acc[3];
    #pragma unroll
    for (int o = 0; o < 3; ++o) acc[o] = bs[o];
    int pbase = (tz + 1) * PZS_ + (yy + 1) * 98 + (xx + 1);
    #pragma unroll 2
    for (int ic = 0; ic < 16; ++ic) {
        const float* xp = t1p + (bb * 16 + ic) * PCS_ + pbase;
        float v[27];
        #pragma unroll
        for (int kz = 0; kz < 3; ++kz)
            #pragma unroll
            for (int ky = 0; ky < 3; ++ky)
                #pragma unroll
                for (int kx = 0; kx < 3; ++kx)
                    v[kz * 9 + ky * 3 + kx] = xp[(kz - 1) * PZS_ + (ky - 1) * 98 + (kx - 1)];
        #pragma unroll
        for (int k = 0; k < 27; ++k)
            #pragma unroll
            for (int o = 0; o < 3; ++o)
                acc[o] = fmaf(ws[ic * 27 + k][o], v[k], acc[o]);
    }
    int sp = tz * 9216 + yy * 96 + xx;
    #pragma unroll
    for (int o = 0; o < 3; ++o) {
        int gi = (bb * 3 + o) * 73728 + sp;
        xr[gi] = acc[o] + x[gi];
    }
}

// ---------------- K4: full featurizer (stores feat) + per-chunk scan carries ----------------
// grid 2304 = 8 XCD * 288
// feat global layout: [f][b][L], f: 0-5 xc, 6-11 dt, 12-17 z, 18-33 B, 34-49 C
// internal sf: 0-5 xc, 6-11 dt, 12-27 B
__global__ __launch_bounds__(128) void k4_carry(const float* __restrict__ xr,
        const float* __restrict__ W_in, const float* __restrict__ W_conv,
        const float* __restrict__ b_conv, const float* __restrict__ W_xproj,
        const float* __restrict__ W_dt, const float* __restrict__ b_dt,
        const float* __restrict__ A_log, float2* __restrict__ carries,
        float* __restrict__ feat) {
    __shared__ float sf[28 * STRD_];
    __shared__ float s_Win[36], s_Wc[24], s_bc[6], s_Wx[198], s_Wdt[6], s_bdt[6];
    int tid = threadIdx.x;
    if (tid < 36) s_Win[tid] = W_in[tid];
    if (tid < 24) s_Wc[tid] = W_conv[tid];
    if (tid >= 36 && tid < 42) s_bc[tid - 36] = b_conv[tid - 36];
    if (tid >= 42 && tid < 48) { s_Wdt[tid - 42] = W_dt[tid - 42]; s_bdt[tid - 42] = b_dt[tid - 42]; }
    if (tid >= 64 && tid < 128) {
        for (int i = tid - 64; i < 198; i += 64) s_Wx[i] = W_xproj[i];
    }
    __syncthreads();
    int bid = blockIdx.x;
    int blk = (bid & 7) * 288 + (bid >> 3);
    int b = blk / NCK_, ck = blk % NCK_;
    int l = ck * CH_ + (tid & (CH_ - 1));
    if (tid < CH_) {
        const float* xb = xr + b * CTHW_;
        float xin[4][6];
        float zv[6];
        #pragma unroll
        for (int k = 0; k < 4; ++k) {
            int r = l - 3 + k;
            float a0 = 0.f, a1 = 0.f, a2v = 0.f;
            if (r >= 0) { a0 = xb[3 * r]; a1 = xb[3 * r + 1]; a2v = xb[3 * r + 2]; }
            #pragma unroll
            for (int d = 0; d < 6; ++d)
                xin[k][d] = s_Win[d * 3] * a0 + s_Win[d * 3 + 1] * a1 + s_Win[d * 3 + 2] * a2v;
            if (k == 3) {
                #pragma unroll
                for (int d = 0; d < 6; ++d)
                    zv[d] = s_Win[(6 + d) * 3] * a0 + s_Win[(6 + d) * 3 + 1] * a1 + s_Win[(6 + d) * 3 + 2] * a2v;
            }
        }
        float xc[6];
        #pragma unroll
        for (int d = 0; d < 6; ++d) {
            float p = s_bc[d];
            #pragma unroll
            for (int k = 0; k < 4; ++k) p = fmaf(s_Wc[d * 4 + k], xin[k][d], p);
            xc[d] = silu_(p);
        }
        float dtraw = 0.f;
        #pragma unroll
        for (int d = 0; d < 6; ++d) dtraw = fmaf(s_Wx[d], xc[d], dtraw);
        #pragma unroll
        for (int d = 0; d < 6; ++d) {
            float dtv = softplus_(fmaf(dtraw, s_Wdt[d], s_bdt[d]));
            sf[(0 + d) * STRD_ + tid] = xc[d];
            sf[(6 + d) * STRD_ + tid] = dtv;
            feat[((0 + d) * 2 + b) * L_ + l] = xc[d];
            feat[((6 + d) * 2 + b) * L_ + l] = dtv;
            feat[((12 + d) * 2 + b) * L_ + l] = zv[d];
        }
        #pragma unroll
        for (int s = 0; s < 16; ++s) {
            float pb = 0.f, pc = 0.f;
            #pragma unroll
            for (int d = 0; d < 6; ++d) {
                pb = fmaf(s_Wx[(1 + s) * 6 + d], xc[d], pb);
                pc = fmaf(s_Wx[(17 + s) * 6 + d], xc[d], pc);
            }
            sf[(12 + s) * STRD_ + tid] = pb;
            feat[((18 + s) * 2 + b) * L_ + l] = pb;
            feat[((34 + s) * 2 + b) * L_ + l] = pc;
        }
    }
    __syncthreads();
    if (tid < 96) {
        int d = tid >> 4, s = tid & 15;
        float a2 = -__expf(A_log[tid]) * LOG2E_;
        float h = 0.f, sdt = 0.f;
        #pragma unroll 8
        for (int i = 0; i < CH_; ++i) {
            float dt = sf[(6 + d) * STRD_ + i];
            float xcv = sf[d * STRD_ + i];
            float Bv = sf[(12 + s) * STRD_ + i];
            h = fmaf(exp2f(dt * a2), h, dt * xcv * Bv);
            sdt += dt;
        }
        carries[(size_t)(b * 96 + tid) * NCK_ + ck] = make_float2(exp2f(sdt * a2), h);
    }
}

// ---------------- K5: parallel scan of carries (one block per (b,r); 2 chunks/thread) ----------------
__global__ __launch_bounds__(576) void k5_scan(const float2* __restrict__ carries,
        float* __restrict__ hpref) {
    __shared__ float2 s0[576], s1[576];
    int t = threadIdx.x;
    int blk = blockIdx.x, b = blk / 96, r = blk % 96;
    const float4* cp = (const float4*)(carries + (size_t)(b * 96 + r) * NCK_);
    float4 cc = cp[t];                          // chunks 2t (x,y) and 2t+1 (z,w)
    float2 c0 = make_float2(cc.x, cc.y);
    s0[t] = make_float2(cc.x * cc.z, cc.z * cc.y + cc.w);   // pair aggregate
    __syncthreads();
    float2* cur = s0;
    float2* nxt = s1;
    for (int off = 1; off < 576; off <<= 1) {
        float2 v = cur[t];
        if (t >= off) {
            float2 p = cur[t - off];
            v = make_float2(p.x * v.x, v.x * p.y + v.y);
        }
        nxt[t] = v;
        __syncthreads();
        float2* tmp = cur; cur = nxt; nxt = tmp;
    }
    float Ey = (t == 0) ? 0.f : cur[t - 1].y;   // state entering chunk 2t
    hpref[(size_t)(b * NCK_ + 2 * t) * 96 + r] = Ey;
    hpref[(size_t)(b * NCK_ + 2 * t + 1) * 96 + r] = fmaf(c0.x, Ey, c0.y);
}

// ---------------- K6: load feat + apply scan + gate + out-proj (swizzled) ----------------
// grid 2304 = 8 XCD * 288; sf fields match feat layout: 0-5 xc, 6-11 dt, 12-17 z, 18-33 B, 34-49 C
__global__ __launch_bounds__(128) void k6_apply(const float* __restrict__ feat,
        const float* __restrict__ A_log, const float* __restrict__ Dp,
        const float* __restrict__ W_out, const float* __restrict__ hpref,
        float* __restrict__ ymp) {
    __shared__ float sf[50 * STRD_];
    __shared__ float ys[CH_ * 7];
    __shared__ float s_wout[18];
    int tid = threadIdx.x;
    if (tid < 18) s_wout[tid] = W_out[tid];
    int bid = blockIdx.x;
    int blk = (bid & 7) * 288 + (bid >> 3);
    int b = blk / NCK_, ck = blk % NCK_;
    int l0 = ck * CH_;
    // cooperative coalesced LDS fill: 50 fields x 64 tokens
    #pragma unroll
    for (int it = 0; it < 25; ++it) {
        int fi = it * 128 + tid;
        int f = fi >> 6, i = fi & 63;
        sf[f * STRD_ + i] = feat[(f * 2 + b) * L_ + l0 + i];
    }
    __syncthreads();
    // --- scan + y, deferred shfl reduction (8-wide batches) ---
    if (tid < 96) {
        int d = tid >> 4, s = tid & 15;
        float a2 = -__expf(A_log[tid]) * LOG2E_;
        float Dd = Dp[d];
        float h = hpref[(size_t)(b * NCK_ + ck) * 96 + tid];
        #pragma unroll 2
        for (int i0 = 0; i0 < CH_; i0 += 8) {
            float pb[8], xv[8];
            #pragma unroll
            for (int j = 0; j < 8; ++j) {
                int i = i0 + j;
                float dt = sf[(6 + d) * STRD_ + i];
                float xcv = sf[d * STRD_ + i];
                float Bv = sf[(18 + s) * STRD_ + i];
                float Cv = sf[(34 + s) * STRD_ + i];
                h = fmaf(exp2f(dt * a2), h, dt * xcv * Bv);
                pb[j] = h * Cv;
                xv[j] = xcv;
            }
            #pragma unroll
            for (int j = 0; j < 8; ++j) pb[j] += __shfl_xor(pb[j], 1, 16);
            #pragma unroll
            for (int j = 0; j < 8; ++j) pb[j] += __shfl_xor(pb[j], 2, 16);
            #pragma unroll
            for (int j = 0; j < 8; ++j) pb[j] += __shfl_xor(pb[j], 4, 16);
            #pragma unroll
            for (int j = 0; j < 8; ++j) pb[j] += __shfl_xor(pb[j], 8, 16);
            if (s == 0) {
                #pragma unroll
                for (int j = 0; j < 8; ++j) {
                    float zz = sf[(12 + d) * STRD_ + i0 + j];
                    ys[(i0 + j) * 7 + d] = fmaf(xv[j], Dd, pb[j]) * silu_(zz);
                }
            }
        }
    }
    __syncthreads();
    // --- out-proj: thread tid (<CH_) handles token l0+tid; write padded ymp interior ---
    if (tid < CH_) {
        int l = l0 + tid;
        float y0 = ys[tid * 7 + 0], y1 = ys[tid * 7 + 1], y2 = ys[tid * 7 + 2];
        float y3 = ys[tid * 7 + 3], y4 = ys[tid * 7 + 4], y5 = ys[tid * 7 + 5];
        int xx = l % 96, yy = (l / 96) % 96, tz = l / 9216;
        int pdst = (tz + 1) * PZS_ + (yy + 1) * 98 + (xx + 1);
        #pragma unroll
        for (int i = 0; i < 3; ++i) {
            float o = s_wout[i * 6 + 0] * y0 + s_wout[i * 6 + 1] * y1
                    + s_wout[i * 6 + 2] * y2 + s_wout[i * 6 + 3] * y3
                    + s_wout[i * 6 + 4] * y4 + s_wout[i * 6 + 5] * y5;
            ymp[(b * 3 + i) * PCS_ + pdst] = o;
        }
    }
}

// ---------------- K7: final conv3d 3->3 + bias (x1, swizzled) ----------------
// grid 576 = 8 XCD * 72
__global__ __launch_bounds__(256, 4) void k7_conv(const float* __restrict__ ymp,
        const float* __restrict__ W, const float* __restrict__ b,
        float* __restrict__ out) {
    __shared__ float ws[81][3];
    __shared__ float bs[3];
    int tid = threadIdx.x;
    for (int i = tid; i < 243; i += 256) ws[i % 81][i / 81] = W[i];
    if (tid < 3) bs[tid] = b[tid];
    __syncthreads();
    int bid = blockIdx.x;
    int swz = (bid & 7) * 72 + (bid >> 3);
    int idx = swz * 256 + tid;
    int xx = idx % 96, yy = (idx / 96) % 96, tz = (idx / 9216) % 8, bb = idx / 73728;
    float acc[3];
    #pragma unroll
    for (int o = 0; o < 3; ++o) acc[o] = bs[o];
    int pbase = (tz + 1) * PZS_ + (yy + 1) * 98 + (xx + 1);
    #pragma unroll
    for (int ic = 0; ic < 3; ++ic) {
        const float* xp = ymp + (bb * 3 + ic) * PCS_ + pbase;
        float v[27];
        #pragma unroll
        for (int kz = 0; kz < 3; ++kz)
            #pragma unroll
            for (int ky = 0; ky < 3; ++ky)
                #pragma unroll
                for (int kx = 0; kx < 3; ++kx)
                    v[kz * 9 + ky * 3 + kx] = xp[(kz - 1) * PZS_ + (ky - 1) * 98 + (kx - 1)];
        #pragma unroll
        for (int k = 0; k < 27; ++k)
            #pragma unroll
            for (int o = 0; o < 3; ++o)
                acc[o] = fmaf(ws[ic * 27 + k][o], v[k], acc[o]);
    }
    int sp = tz * 9216 + yy * 96 + xx;
    #pragma unroll
    for (int o = 0; o < 3; ++o) out[(bb * 3 + o) * 73728 + sp] = acc[o];
}

extern "C" void kernel_launch(void* const* d_in, const int* in_sizes, int n_in,
                              void* d_out, int out_size, void* d_ws, size_t ws_size,
                              hipStream_t stream) {
    const float* x      = (const float*)d_in[0];
    const float* W_cb1  = (const float*)d_in[1];
    const float* b_cb1  = (const float*)d_in[2];
    const float* W_cb2  = (const float*)d_in[3];
    const float* b_cb2  = (const float*)d_in[4];
    const float* W_in   = (const float*)d_in[5];
    const float* W_conv = (const float*)d_in[6];
    const float* b_conv = (const float*)d_in[7];
    const float* W_xpr  = (const float*)d_in[8];
    const float* W_dt   = (const float*)d_in[9];
    const float* b_dt   = (const float*)d_in[10];
    const float* A_log  = (const float*)d_in[11];
    const float* Dp     = (const float*)d_in[12];
    const float* W_out  = (const float*)d_in[13];
    const float* W_sm   = (const float*)d_in[14];
    const float* b_sm   = (const float*)d_in[15];

    float* ws    = (float*)d_ws;
    float* xpad  = ws;                        // XPAD_N
    float* t1p   = xpad + XPAD_N;             // T1P_N
    float* ymp   = t1p + T1P_N;               // YMP_N
    float* xr    = ws + ZERO_N;               // 442368
    float2* carr = (float2*)(xr + 442368);    // 2*96*1152 float2 = 442368 floats
    float* hpref = xr + 442368 + 442368;      // 2*1152*96 = 221184
    float* feat  = hpref + 221184;            // 50*2*73728 = 7372800
    float* out   = (float*)d_out;

    int n4 = ZERO_N / 4;
    k0_zero<<<(n4 + 255) / 256, 256, 0, stream>>>((float4*)ws, n4);
    k0_copy<<<1728, 256, 0, stream>>>(x, xpad);
    k1_conv<<<576, 256, 0, stream>>>(xpad, W_cb1, b_cb1, t1p);
    k2_conv<<<576, 256, 0, stream>>>(t1p, W_cb2, b_cb2, x, xr);
    k4_carry<<<2304, 128, 0, stream>>>(xr, W_in, W_conv, b_conv, W_xpr, W_dt, b_dt,
                                       A_log, carr, feat);
    k5_scan<<<192, 576, 0, stream>>>(carr, hpref);
    k6_apply<<<2304, 128, 0, stream>>>(feat, A_log, Dp, W_out, hpref, ymp);
    k7_conv<<<576, 256, 0, stream>>>(ymp, W_sm, b_sm, out);
}